// Round 3
// baseline (148.604 us; speedup 1.0000x reference)
//
#include <hip/hip_runtime.h>

#define HH 80
#define WW 80
#define NPIX 6400          // 80*80
#define NB 4
#define BN 25600           // NB * NPIX
#define CDIM 256
#define QKVC 768
#define SCALE 0.17677669529663689f   // 32^-0.5

typedef __attribute__((ext_vector_type(8))) short short8;
typedef __attribute__((ext_vector_type(4))) float floatx4;

__device__ __forceinline__ float b2f(ushort u) {
    return __uint_as_float(((uint)u) << 16);
}
__device__ __forceinline__ ushort f2b(float f) {
    uint u = __float_as_uint(f);
    return (ushort)((u + 0x7fffu + ((u >> 16) & 1u)) >> 16);   // RNE
}
__device__ __forceinline__ void unpack8(uint4 v, float* f) {
    f[0] = __uint_as_float(v.x << 16); f[1] = __uint_as_float(v.x & 0xffff0000u);
    f[2] = __uint_as_float(v.y << 16); f[3] = __uint_as_float(v.y & 0xffff0000u);
    f[4] = __uint_as_float(v.z << 16); f[5] = __uint_as_float(v.z & 0xffff0000u);
    f[6] = __uint_as_float(v.w << 16); f[7] = __uint_as_float(v.w & 0xffff0000u);
}
__device__ __forceinline__ void gload_lds16(const void* gptr, void* lptr) {
    __builtin_amdgcn_global_load_lds(
        (const __attribute__((address_space(1))) unsigned int*)gptr,
        (__attribute__((address_space(3))) unsigned int*)lptr,
        16, 0, 0);
}

// ---------------------------------------------------------------------------
// Fused cast kernel.
//  blocks x <  100: Yb[n][c] = bf16(concat(rgb, ir)) via LDS transpose tile
//  blocks x >= 100: cast w_qkv / w_proj to bf16 (flat)
// ---------------------------------------------------------------------------
__global__ __launch_bounds__(256) void cast_all_k(
    const float* __restrict__ rgb, const float* __restrict__ ir,
    const float* __restrict__ wq, const float* __restrict__ wp,
    ushort* __restrict__ Yb, ushort* __restrict__ wqb, ushort* __restrict__ wpb)
{
    const int tid = threadIdx.x;
    if (blockIdx.x >= 100) {
        int i = (((blockIdx.x - 100) * 8 + blockIdx.y) * 4 + blockIdx.z) * 256 + tid;
        if (i < QKVC * CDIM) wqb[i] = f2b(wq[i]);
        else                 wpb[i - QKVC * CDIM] = f2b(wp[i - QKVC * CDIM]);
        return;
    }
    __shared__ ushort T[32][72];
    const int pix0 = blockIdx.x * 64;
    const int cb = blockIdx.y;
    const int b = blockIdx.z;

    const int pl = tid & 63, cg = tid >> 6;
    #pragma unroll
    for (int cc = 0; cc < 32; cc += 4) {
        int c = cb * 32 + cc + cg;
        const float* src = (c < 128) ? (rgb + ((size_t)b * 128 + c) * NPIX)
                                     : (ir + ((size_t)b * 128 + (c - 128)) * NPIX);
        T[cc + cg][pl] = f2b(src[pix0 + pl]);
    }
    __syncthreads();
    const int nl = tid >> 2, c0 = (tid & 3) * 8;
    ushort tmp[8];
    #pragma unroll
    for (int j = 0; j < 8; ++j) tmp[j] = T[c0 + j][nl];
    uint4 v;
    v.x = tmp[0] | ((uint)tmp[1] << 16);
    v.y = tmp[2] | ((uint)tmp[3] << 16);
    v.z = tmp[4] | ((uint)tmp[5] << 16);
    v.w = tmp[6] | ((uint)tmp[7] << 16);
    *(uint4*)(&Yb[((size_t)(b * NPIX + pix0 + nl)) * CDIM + cb * 32 + c0]) = v;
}

// ---------------------------------------------------------------------------
// BK=64 MFMA NT GEMM body. 128x128 tile, 4 K-iters. Unpadded LDS [m][64] with
// parity-XOR swizzle: odd rows store their two 32-elem k-halves swapped
// (scol = k ^ ((row&1)<<5)), applied on the GLOBAL address so the
// global_load_lds DMA stays flat+contiguous (m104). Frag reads spread across
// all 32 banks -> conflict-free.
// MFMA operands swapped (o = A operand): acc reg r = o offset, lane&15 = n.
// ---------------------------------------------------------------------------
__device__ __forceinline__ void gemm_nt_body64(
    const ushort* __restrict__ A, const ushort* __restrict__ W,
    ushort* As, ushort* Bs, int n0, int o0, floatx4 acc[4][4])
{
    const int tid = threadIdx.x;
    const int lane = tid & 63;
    const int wave = tid >> 6;
    const int wr = wave >> 1, wc = wave & 1;
    const int l15 = lane & 15, quad = lane >> 4;

    const int srow8 = tid >> 3;                        // row within 32-row round
    const int scol  = ((tid & 7) * 8) ^ ((srow8 & 1) << 5);
    const int par   = l15 & 1;                         // frag-row parity

    for (int k0 = 0; k0 < CDIM; k0 += 64) {
        #pragma unroll
        for (int r = 0; r < 4; ++r) {
            const int row = r * 32 + srow8;
            gload_lds16(&A[(size_t)(n0 + row) * CDIM + k0 + scol],
                        As + r * 2048 + wave * 512);
            gload_lds16(&W[(size_t)(o0 + row) * CDIM + k0 + scol],
                        Bs + r * 2048 + wave * 512);
        }
        __syncthreads();
        #pragma unroll
        for (int s = 0; s < 2; ++s) {
            const int fc = ((s ^ par) << 5) + quad * 8;
            short8 af[4], bfr[4];
            #pragma unroll
            for (int i = 0; i < 4; ++i)
                af[i] = *(const short8*)(&As[(wr * 64 + i * 16 + l15) * 64 + fc]);
            #pragma unroll
            for (int j = 0; j < 4; ++j)
                bfr[j] = *(const short8*)(&Bs[(wc * 64 + j * 16 + l15) * 64 + fc]);
            #pragma unroll
            for (int i = 0; i < 4; ++i)
                #pragma unroll
                for (int j = 0; j < 4; ++j)
                    acc[i][j] = __builtin_amdgcn_mfma_f32_16x16x32_bf16(
                        bfr[j], af[i], acc[i][j], 0, 0, 0);   // swapped: rows=o
        }
        __syncthreads();
    }
}

// ---------------------------------------------------------------------------
// QKV GEMM. Output chunk-major qkv2[chunk][n][32], chunk = o>>5
// (chunk 0..7 = Q(dil,head), 8..15 = K, 16..23 = V). 8B packed stores.
// XCD-chunked dispatch: 1200 blocks, bid%8 selects XCD (round-robin HW map);
// within an XCD's 150 consecutive slots, o iterates fastest so the 6 o-blocks
// sharing one A-tile (64 KB of Yb) run back-to-back on the same XCD -> 5/6
// A reads become L2 hits; all of W (384 KB) stays L2-resident per XCD.
// ---------------------------------------------------------------------------
__global__ __launch_bounds__(256) void gemm_qkv_mfma(
    const ushort* __restrict__ Yb, const ushort* __restrict__ Wb,
    ushort* __restrict__ qkv2)
{
    __shared__ __align__(16) ushort As[128 * 64];
    __shared__ __align__(16) ushort Bs[128 * 64];
    const int tid = threadIdx.x;
    const int lane = tid & 63;
    const int wave = tid >> 6;
    const int wr = wave >> 1, wc = wave & 1;
    const int l15 = lane & 15, quad = lane >> 4;

    const int bid = blockIdx.x;                  // grid = 1200 linear
    const int swz = (bid & 7) * 150 + (bid >> 3);
    const int n0 = (swz / 6) * 128;
    const int o0 = (swz % 6) * 128;

    floatx4 acc[4][4] = {};
    gemm_nt_body64(Yb, Wb, As, Bs, n0, o0, acc);

    #pragma unroll
    for (int i = 0; i < 4; ++i) {
        const int n = n0 + wr * 64 + i * 16 + l15;
        #pragma unroll
        for (int j = 0; j < 4; ++j) {
            const int o4 = o0 + wc * 64 + j * 16 + quad * 4;   // 4 consecutive o
            uint2 v;
            v.x = f2b(acc[i][j][0]) | ((uint)f2b(acc[i][j][1]) << 16);
            v.y = f2b(acc[i][j][2]) | ((uint)f2b(acc[i][j][3]) << 16);
            *(uint2*)(qkv2 + (size_t)(o4 >> 5) * BN * 32 + (size_t)n * 32 + (o4 & 31)) = v;
        }
    }
}

// ---------------------------------------------------------------------------
// Tiled dilated local attention. One block = (b, dil, head) x 16x16 tile.
// T14 async-STAGE: K staged via global_load_lds DMA; V loaded to REGISTERS
// up-front (latency hides under QK compute), then ds_write'd into the same
// LDS buffer after the post-QK barrier. One exposed vm-drain per block
// (was two: K drain + V drain with only ~40 VALU of softmax covering it).
// EDGE=false (interior tiles, 9/25): no clamps/masks. OOB (EDGE): score 0
// in softmax denom, value 0.
// ---------------------------------------------------------------------------
template<int D, bool EDGE>
__device__ __forceinline__ void attn_tile(
    const ushort* __restrict__ qkv2, ushort* __restrict__ X2,
    ushort* kl, int b, int dh, int y0, int x0)
{
    constexpr int RW = 16 + 2 * D;
    constexpr int RP = RW * RW;
    constexpr int NIT = (RP + 63) / 64;     // 7 for D=2, 8 for D=3
    const int tid = threadIdx.x;
    const int lane = tid & 63;
    const int wave = tid >> 6;          // = channel chunk c (0..3) for staging
    const ushort* Qc = qkv2 + (size_t)dh * BN * 32;
    const ushort* Kc = qkv2 + (size_t)(8 + dh) * BN * 32;
    const ushort* Vc = qkv2 + (size_t)(16 + dh) * BN * 32;

    const int px = tid & 15, py = tid >> 4;
    const int n = b * NPIX + (y0 + py) * WW + (x0 + px);
    float q[32];
    {
        const uint4* qp = (const uint4*)(Qc + (size_t)n * 32);
        uint4 v0 = qp[0], v1 = qp[1], v2 = qp[2], v3 = qp[3];
        unpack8(v0, q); unpack8(v1, q + 8); unpack8(v2, q + 16); unpack8(v3, q + 24);
    }

    // phase 1a: stage K region via DMA (wave w = channel chunk w; LDS [c][p][16B])
    #pragma unroll 2
    for (int p0 = 0; p0 < RP; p0 += 64) {
        int p = p0 + lane;
        int ry = p / RW, rx = p % RW;
        int gy = y0 - D + ry, gx = x0 - D + rx;
        if (EDGE) { gy = min(max(gy, 0), HH - 1); gx = min(max(gx, 0), WW - 1); }
        if (p < RP)
            gload_lds16(Kc + (size_t)(b * NPIX + gy * WW + gx) * 32 + wave * 8,
                        kl + (size_t)(wave * RP + p0) * 8);
    }
    // phase 1b: issue V loads to registers (land while QK computes)
    uint4 vreg[NIT];
    #pragma unroll
    for (int it = 0; it < NIT; ++it) {
        int p = it * 64 + lane;
        int pc = (p < RP) ? p : (RP - 1);
        int ry = pc / RW, rx = pc % RW;
        int gy = y0 - D + ry, gx = x0 - D + rx;
        if (EDGE) { gy = min(max(gy, 0), HH - 1); gx = min(max(gx, 0), WW - 1); }
        vreg[it] = *(const uint4*)(Vc + (size_t)(b * NPIX + gy * WW + gx) * 32 + wave * 8);
    }
    __syncthreads();                    // K DMA landed (V reg-loads also drained)

    float sc[9];
    #pragma unroll
    for (int t = 0; t < 9; ++t) {
        const int dy = t / 3 - 1, dx = t % 3 - 1;
        const int p = (py + D + dy * D) * RW + (px + D + dx * D);
        float s = 0.f;
        bool ok = true;
        if (EDGE) {
            const int yy = y0 + py + dy * D, xx = x0 + px + dx * D;
            ok = (yy >= 0 && yy < HH && xx >= 0 && xx < WW);
        }
        if (ok) {
            #pragma unroll
            for (int c = 0; c < 4; ++c) {
                float kv[8];
                unpack8(*(const uint4*)(kl + (size_t)(c * RP + p) * 8), kv);
                #pragma unroll
                for (int j = 0; j < 8; ++j) s += q[c * 8 + j] * kv[j];
            }
        }
        sc[t] = s * SCALE;              // OOB stays exactly 0 (in softmax denom)
    }
    __syncthreads();                    // all waves done reading K

    // phase 2: V regs -> LDS (cheap ds_writes), softmax math in parallel
    #pragma unroll
    for (int it = 0; it < NIT; ++it) {
        int p = it * 64 + lane;
        if (p < RP)
            *(uint4*)(kl + (size_t)(wave * RP + p) * 8) = vreg[it];
    }

    float m = sc[0];
    #pragma unroll
    for (int t = 1; t < 9; ++t) m = fmaxf(m, sc[t]);
    float sum = 0.f;
    #pragma unroll
    for (int t = 0; t < 9; ++t) { sc[t] = __expf(sc[t] - m); sum += sc[t]; }
    const float inv = 1.f / sum;
    __syncthreads();                    // V writes visible (lgkm drain only)

    float o[32];
    #pragma unroll
    for (int hd = 0; hd < 32; ++hd) o[hd] = 0.f;
    #pragma unroll
    for (int t = 0; t < 9; ++t) {
        const int dy = t / 3 - 1, dx = t % 3 - 1;
        const int p = (py + D + dy * D) * RW + (px + D + dx * D);
        bool ok = true;
        if (EDGE) {
            const int yy = y0 + py + dy * D, xx = x0 + px + dx * D;
            ok = (yy >= 0 && yy < HH && xx >= 0 && xx < WW);
        }
        if (ok) {
            const float wgt = sc[t] * inv;
            #pragma unroll
            for (int c = 0; c < 4; ++c) {
                float vv[8];
                unpack8(*(const uint4*)(kl + (size_t)(c * RP + p) * 8), vv);
                #pragma unroll
                for (int j = 0; j < 8; ++j) o[c * 8 + j] += wgt * vv[j];
            }
        }
    }
    uint4* xp = (uint4*)(X2 + (size_t)dh * BN * 32 + (size_t)n * 32);
    #pragma unroll
    for (int m4 = 0; m4 < 4; ++m4) {
        uint4 v;
        v.x = f2b(o[8 * m4 + 0]) | ((uint)f2b(o[8 * m4 + 1]) << 16);
        v.y = f2b(o[8 * m4 + 2]) | ((uint)f2b(o[8 * m4 + 3]) << 16);
        v.z = f2b(o[8 * m4 + 4]) | ((uint)f2b(o[8 * m4 + 5]) << 16);
        v.w = f2b(o[8 * m4 + 6]) | ((uint)f2b(o[8 * m4 + 7]) << 16);
        xp[m4] = v;
    }
}

__global__ __launch_bounds__(256) void attn2_k(
    const ushort* __restrict__ qkv2, ushort* __restrict__ X2)
{
    __shared__ __align__(16) ushort kl[4 * 484 * 8];   // 31 KB (worst case d=3)
    const int tile = blockIdx.x;                       // 0..24
    const int y0 = (tile / 5) * 16, x0 = (tile % 5) * 16;
    const int dh = blockIdx.y;                         // dil*4 + head
    const int b = blockIdx.z;
    const bool inter = (y0 >= 16 && y0 <= 48 && x0 >= 16 && x0 <= 48);
    if (dh < 4) {
        if (inter) attn_tile<2, false>(qkv2, X2, kl, b, dh, y0, x0);
        else       attn_tile<2, true >(qkv2, X2, kl, b, dh, y0, x0);
    } else {
        if (inter) attn_tile<3, false>(qkv2, X2, kl, b, dh, y0, x0);
        else       attn_tile<3, true >(qkv2, X2, kl, b, dh, y0, x0);
    }
}

// ---------------------------------------------------------------------------
// Proj GEMM + epilogue: out[n][co] = X·Wp^T + bias + Y residual.
// Retiled 64n x 128o: 800 blocks (~3/CU co-resident). LDS 24 KB. 4 waves in
// 2x2 grid, each 32n x 64o, acc[2][4]. A staged from chunk-major X2: the XOR
// swizzle's bit-5 flip selects between the two 32-wide chunks spanned by
// BK=64 (chunk_sel). XCD-chunked dispatch like qkv (o fastest: A-tile
// L2-reuse across 2 o-blocks; W 128 KB L2-resident).
// ---------------------------------------------------------------------------
__global__ __launch_bounds__(256) void proj_mfma(
    const ushort* __restrict__ X2, const ushort* __restrict__ Wpb,
    const float* __restrict__ bp, const ushort* __restrict__ Yb,
    float* __restrict__ out)
{
    __shared__ __align__(16) ushort As[64 * 64];       //  8 KB
    __shared__ __align__(16) ushort Bs[128 * 64];      // 16 KB
    const int tid = threadIdx.x;
    const int lane = tid & 63;
    const int wave = tid >> 6;
    const int wr = wave >> 1, wc = wave & 1;
    const int l15 = lane & 15, quad = lane >> 4;

    const int bid = blockIdx.x;                  // grid = 800 linear
    const int swz = (bid & 7) * 100 + (bid >> 3);
    const int n0 = (swz >> 1) * 64;
    const int o0 = (swz & 1) * 128;

    const int srow8 = tid >> 3;
    const int scol  = ((tid & 7) * 8) ^ ((srow8 & 1) << 5);
    const int chunk_sel = ((tid >> 2) & 1) ^ (srow8 & 1);
    const int coff  = (tid & 3) * 8;
    const int par   = l15 & 1;

    floatx4 acc[2][4] = {};

    for (int k0 = 0; k0 < CDIM; k0 += 64) {
        const int cbase = k0 >> 5;
        const ushort* Achunk = X2 + (size_t)(cbase + chunk_sel) * BN * 32;
        #pragma unroll
        for (int r = 0; r < 2; ++r) {
            const int row = r * 32 + srow8;
            gload_lds16(&Achunk[(size_t)(n0 + row) * 32 + coff],
                        As + r * 2048 + wave * 512);
        }
        #pragma unroll
        for (int r = 0; r < 4; ++r) {
            const int row = r * 32 + srow8;
            gload_lds16(&Wpb[(size_t)(o0 + row) * CDIM + k0 + scol],
                        Bs + r * 2048 + wave * 512);
        }
        __syncthreads();
        #pragma unroll
        for (int s = 0; s < 2; ++s) {
            const int fc = ((s ^ par) << 5) + quad * 8;
            short8 af[2], bfr[4];
            #pragma unroll
            for (int i = 0; i < 2; ++i)
                af[i] = *(const short8*)(&As[(wr * 32 + i * 16 + l15) * 64 + fc]);
            #pragma unroll
            for (int j = 0; j < 4; ++j)
                bfr[j] = *(const short8*)(&Bs[(wc * 64 + j * 16 + l15) * 64 + fc]);
            #pragma unroll
            for (int i = 0; i < 2; ++i)
                #pragma unroll
                for (int j = 0; j < 4; ++j)
                    acc[i][j] = __builtin_amdgcn_mfma_f32_16x16x32_bf16(
                        bfr[j], af[i], acc[i][j], 0, 0, 0);   // swapped: rows=o
        }
        __syncthreads();
    }

    #pragma unroll
    for (int i = 0; i < 2; ++i) {
        const int n = n0 + wr * 32 + i * 16 + l15;
        #pragma unroll
        for (int j = 0; j < 4; ++j) {
            const int o4 = o0 + wc * 64 + j * 16 + quad * 4;   // 4 consecutive co
            const float4 bias = *(const float4*)(bp + o4);
            const ushort4 res = *(const ushort4*)(Yb + (size_t)n * CDIM + o4);
            float4 v;
            v.x = acc[i][j][0] + bias.x + b2f(res.x);
            v.y = acc[i][j][1] + bias.y + b2f(res.y);
            v.z = acc[i][j][2] + bias.z + b2f(res.z);
            v.w = acc[i][j][3] + bias.w + b2f(res.w);
            *(float4*)(out + (size_t)n * CDIM + o4) = v;
        }
    }
}

extern "C" void kernel_launch(void* const* d_in, const int* in_sizes, int n_in,
                              void* d_out, int out_size, void* d_ws, size_t ws_size,
                              hipStream_t stream) {
    const float* rgb    = (const float*)d_in[0];
    const float* ir     = (const float*)d_in[1];
    const float* w_qkv  = (const float*)d_in[2];
    const float* w_proj = (const float*)d_in[3];
    const float* b_proj = (const float*)d_in[4];
    float* out = (float*)d_out;

    ushort* qkv2 = (ushort*)d_ws;                    // 24 chunks * 25600*32 = 39.3 MB
    ushort* Yb   = qkv2 + (size_t)24 * BN * 32;      // 25600*256 = 13.1 MB
    ushort* X2   = Yb + (size_t)BN * CDIM;           // 8 chunks * 25600*32 = 13.1 MB
    ushort* Wqb  = X2 + (size_t)8 * BN * 32;         // 768*256
    ushort* Wpb  = Wqb + (size_t)QKVC * CDIM;        // 256*256

    cast_all_k<<<dim3(132, 8, NB), 256, 0, stream>>>(rgb, ir, w_qkv, w_proj,
                                                     Yb, Wqb, Wpb);
    gemm_qkv_mfma<<<dim3(1200), 256, 0, stream>>>(Yb, Wqb, qkv2);
    attn2_k<<<dim3(25, 8, NB), 256, 0, stream>>>(qkv2, X2);
    proj_mfma<<<dim3(800), 256, 0, stream>>>(X2, Wpb, b_proj, Yb, out);
}

// Round 4
// 140.170 us; speedup vs baseline: 1.0602x; 1.0602x over previous
//
#include <hip/hip_runtime.h>

#define HH 80
#define WW 80
#define NPIX 6400          // 80*80
#define NB 4
#define BN 25600           // NB * NPIX
#define CDIM 256
#define QKVC 768
#define SCALE 0.17677669529663689f   // 32^-0.5

typedef __attribute__((ext_vector_type(8))) short short8;
typedef __attribute__((ext_vector_type(4))) float floatx4;

__device__ __forceinline__ float b2f(ushort u) {
    return __uint_as_float(((uint)u) << 16);
}
__device__ __forceinline__ ushort f2b(float f) {
    uint u = __float_as_uint(f);
    return (ushort)((u + 0x7fffu + ((u >> 16) & 1u)) >> 16);   // RNE
}
__device__ __forceinline__ void unpack8(uint4 v, float* f) {
    f[0] = __uint_as_float(v.x << 16); f[1] = __uint_as_float(v.x & 0xffff0000u);
    f[2] = __uint_as_float(v.y << 16); f[3] = __uint_as_float(v.y & 0xffff0000u);
    f[4] = __uint_as_float(v.z << 16); f[5] = __uint_as_float(v.z & 0xffff0000u);
    f[6] = __uint_as_float(v.w << 16); f[7] = __uint_as_float(v.w & 0xffff0000u);
}
__device__ __forceinline__ void gload_lds16(const void* gptr, void* lptr) {
    __builtin_amdgcn_global_load_lds(
        (const __attribute__((address_space(1))) unsigned int*)gptr,
        (__attribute__((address_space(3))) unsigned int*)lptr,
        16, 0, 0);
}

// ---------------------------------------------------------------------------
// Fused cast kernel.
//  blocks x <  100: Yb[n][c] = bf16(concat(rgb, ir)) via LDS transpose tile
//  blocks x >= 100: cast w_qkv / w_proj to bf16 (flat)
// ---------------------------------------------------------------------------
__global__ __launch_bounds__(256) void cast_all_k(
    const float* __restrict__ rgb, const float* __restrict__ ir,
    const float* __restrict__ wq, const float* __restrict__ wp,
    ushort* __restrict__ Yb, ushort* __restrict__ wqb, ushort* __restrict__ wpb)
{
    const int tid = threadIdx.x;
    if (blockIdx.x >= 100) {
        int i = (((blockIdx.x - 100) * 8 + blockIdx.y) * 4 + blockIdx.z) * 256 + tid;
        if (i < QKVC * CDIM) wqb[i] = f2b(wq[i]);
        else                 wpb[i - QKVC * CDIM] = f2b(wp[i - QKVC * CDIM]);
        return;
    }
    __shared__ ushort T[32][72];
    const int pix0 = blockIdx.x * 64;
    const int cb = blockIdx.y;
    const int b = blockIdx.z;

    const int pl = tid & 63, cg = tid >> 6;
    #pragma unroll
    for (int cc = 0; cc < 32; cc += 4) {
        int c = cb * 32 + cc + cg;
        const float* src = (c < 128) ? (rgb + ((size_t)b * 128 + c) * NPIX)
                                     : (ir + ((size_t)b * 128 + (c - 128)) * NPIX);
        T[cc + cg][pl] = f2b(src[pix0 + pl]);
    }
    __syncthreads();
    const int nl = tid >> 2, c0 = (tid & 3) * 8;
    ushort tmp[8];
    #pragma unroll
    for (int j = 0; j < 8; ++j) tmp[j] = T[c0 + j][nl];
    uint4 v;
    v.x = tmp[0] | ((uint)tmp[1] << 16);
    v.y = tmp[2] | ((uint)tmp[3] << 16);
    v.z = tmp[4] | ((uint)tmp[5] << 16);
    v.w = tmp[6] | ((uint)tmp[7] << 16);
    *(uint4*)(&Yb[((size_t)(b * NPIX + pix0 + nl)) * CDIM + cb * 32 + c0]) = v;
}

// ---------------------------------------------------------------------------
// BK=64 MFMA NT GEMM body. 128x128 tile, 4 K-iters. Unpadded LDS [m][64] with
// parity-XOR swizzle: odd rows store their two 32-elem k-halves swapped
// (scol = k ^ ((row&1)<<5)), applied on the GLOBAL address so the
// global_load_lds DMA stays flat+contiguous (m104). Frag reads spread across
// all 32 banks -> conflict-free.
// MFMA operands swapped (o = A operand): acc reg r = o offset, lane&15 = n.
// ---------------------------------------------------------------------------
__device__ __forceinline__ void gemm_nt_body64(
    const ushort* __restrict__ A, const ushort* __restrict__ W,
    ushort* As, ushort* Bs, int n0, int o0, floatx4 acc[4][4])
{
    const int tid = threadIdx.x;
    const int lane = tid & 63;
    const int wave = tid >> 6;
    const int wr = wave >> 1, wc = wave & 1;
    const int l15 = lane & 15, quad = lane >> 4;

    const int srow8 = tid >> 3;                        // row within 32-row round
    const int scol  = ((tid & 7) * 8) ^ ((srow8 & 1) << 5);
    const int par   = l15 & 1;                         // frag-row parity

    for (int k0 = 0; k0 < CDIM; k0 += 64) {
        #pragma unroll
        for (int r = 0; r < 4; ++r) {
            const int row = r * 32 + srow8;
            gload_lds16(&A[(size_t)(n0 + row) * CDIM + k0 + scol],
                        As + r * 2048 + wave * 512);
            gload_lds16(&W[(size_t)(o0 + row) * CDIM + k0 + scol],
                        Bs + r * 2048 + wave * 512);
        }
        __syncthreads();
        #pragma unroll
        for (int s = 0; s < 2; ++s) {
            const int fc = ((s ^ par) << 5) + quad * 8;
            short8 af[4], bfr[4];
            #pragma unroll
            for (int i = 0; i < 4; ++i)
                af[i] = *(const short8*)(&As[(wr * 64 + i * 16 + l15) * 64 + fc]);
            #pragma unroll
            for (int j = 0; j < 4; ++j)
                bfr[j] = *(const short8*)(&Bs[(wc * 64 + j * 16 + l15) * 64 + fc]);
            #pragma unroll
            for (int i = 0; i < 4; ++i)
                #pragma unroll
                for (int j = 0; j < 4; ++j)
                    acc[i][j] = __builtin_amdgcn_mfma_f32_16x16x32_bf16(
                        bfr[j], af[i], acc[i][j], 0, 0, 0);   // swapped: rows=o
        }
        __syncthreads();
    }
}

// ---------------------------------------------------------------------------
// QKV GEMM. Output chunk-major qkv2[chunk][n][32], chunk = o>>5
// (chunk 0..7 = Q(dil,head), 8..15 = K, 16..23 = V). 8B packed stores.
// XCD-chunked dispatch: 1200 blocks, bid%8 selects XCD (round-robin HW map);
// within an XCD's 150 consecutive slots, o iterates fastest so the 6 o-blocks
// sharing one A-tile (64 KB of Yb) run back-to-back on the same XCD -> 5/6
// A reads become L2 hits; all of W (384 KB) stays L2-resident per XCD.
// ---------------------------------------------------------------------------
__global__ __launch_bounds__(256) void gemm_qkv_mfma(
    const ushort* __restrict__ Yb, const ushort* __restrict__ Wb,
    ushort* __restrict__ qkv2)
{
    __shared__ __align__(16) ushort As[128 * 64];
    __shared__ __align__(16) ushort Bs[128 * 64];
    const int tid = threadIdx.x;
    const int lane = tid & 63;
    const int wave = tid >> 6;
    const int wr = wave >> 1, wc = wave & 1;
    const int l15 = lane & 15, quad = lane >> 4;

    const int bid = blockIdx.x;                  // grid = 1200 linear
    const int swz = (bid & 7) * 150 + (bid >> 3);
    const int n0 = (swz / 6) * 128;
    const int o0 = (swz % 6) * 128;

    floatx4 acc[4][4] = {};
    gemm_nt_body64(Yb, Wb, As, Bs, n0, o0, acc);

    #pragma unroll
    for (int i = 0; i < 4; ++i) {
        const int n = n0 + wr * 64 + i * 16 + l15;
        #pragma unroll
        for (int j = 0; j < 4; ++j) {
            const int o4 = o0 + wc * 64 + j * 16 + quad * 4;   // 4 consecutive o
            uint2 v;
            v.x = f2b(acc[i][j][0]) | ((uint)f2b(acc[i][j][1]) << 16);
            v.y = f2b(acc[i][j][2]) | ((uint)f2b(acc[i][j][3]) << 16);
            *(uint2*)(qkv2 + (size_t)(o4 >> 5) * BN * 32 + (size_t)n * 32 + (o4 & 31)) = v;
        }
    }
}

// ---------------------------------------------------------------------------
// Dilated local attention, NO-LDS direct-L2 version. One thread = one output
// pixel; one block = (b, dil, head) x 16x16 tile, 4 free-running waves, zero
// barriers, zero LDS. Rationale (R3 counters): staged version was latency-
// bound (Occupancy 0.19%, VALUBusy 0.33%) while K+V per (dil,head) is only
// 3.2 MB -- fits one XCD's 4 MB L2 with 9x reuse served from L2 (guide
// common-mistake #7: don't stage what cache-fits). XCD swizzle: bid&7 == dh
// so each XCD owns exactly one (dil,head) K/V working set.
// OOB semantics: score 0 participates in softmax denom; V contribution 0.
// ---------------------------------------------------------------------------
template<int D, bool EDGE>
__device__ __forceinline__ void attn_px(
    const ushort* __restrict__ qkv2, ushort* __restrict__ X2,
    int b, int dh, int y0, int x0)
{
    const int tid = threadIdx.x;
    const int px = tid & 15, py = tid >> 4;
    const int yy0 = y0 + py, xx0 = x0 + px;
    const int n = b * NPIX + yy0 * WW + xx0;
    const ushort* Qc = qkv2 + (size_t)dh * BN * 32;
    const ushort* Kc = qkv2 + (size_t)(8 + dh) * BN * 32;
    const ushort* Vc = qkv2 + (size_t)(16 + dh) * BN * 32;

    float q[32];
    {
        const uint4* qp = (const uint4*)(Qc + (size_t)n * 32);
        uint4 v0 = qp[0], v1 = qp[1], v2 = qp[2], v3 = qp[3];
        unpack8(v0, q); unpack8(v1, q + 8); unpack8(v2, q + 16); unpack8(v3, q + 24);
    }

    float sc[9];
    #pragma unroll
    for (int t = 0; t < 9; ++t) {
        const int dy = t / 3 - 1, dx = t % 3 - 1;
        int yy = yy0 + dy * D, xx = xx0 + dx * D;
        bool ok = true;
        if (EDGE) {
            ok = (yy >= 0 && yy < HH && xx >= 0 && xx < WW);
            yy = min(max(yy, 0), HH - 1);
            xx = min(max(xx, 0), WW - 1);
        }
        const uint4* kp = (const uint4*)(Kc + (size_t)(b * NPIX + yy * WW + xx) * 32);
        uint4 k0 = kp[0], k1 = kp[1], k2 = kp[2], k3 = kp[3];
        float kv[32];
        unpack8(k0, kv); unpack8(k1, kv + 8); unpack8(k2, kv + 16); unpack8(k3, kv + 24);
        float s = 0.f;
        #pragma unroll
        for (int j = 0; j < 32; ++j) s += q[j] * kv[j];
        sc[t] = (EDGE && !ok) ? 0.f : s * SCALE;   // OOB: exact 0 (in denom)
    }

    float m = sc[0];
    #pragma unroll
    for (int t = 1; t < 9; ++t) m = fmaxf(m, sc[t]);
    float sum = 0.f;
    #pragma unroll
    for (int t = 0; t < 9; ++t) { sc[t] = __expf(sc[t] - m); sum += sc[t]; }
    const float inv = 1.f / sum;

    float o[32];
    #pragma unroll
    for (int j = 0; j < 32; ++j) o[j] = 0.f;
    #pragma unroll
    for (int t = 0; t < 9; ++t) {
        const int dy = t / 3 - 1, dx = t % 3 - 1;
        int yy = yy0 + dy * D, xx = xx0 + dx * D;
        bool ok = true;
        if (EDGE) {
            ok = (yy >= 0 && yy < HH && xx >= 0 && xx < WW);
            yy = min(max(yy, 0), HH - 1);
            xx = min(max(xx, 0), WW - 1);
        }
        const uint4* vp = (const uint4*)(Vc + (size_t)(b * NPIX + yy * WW + xx) * 32);
        uint4 v0 = vp[0], v1 = vp[1], v2 = vp[2], v3 = vp[3];
        float vv[32];
        unpack8(v0, vv); unpack8(v1, vv + 8); unpack8(v2, vv + 16); unpack8(v3, vv + 24);
        const float wgt = (EDGE && !ok) ? 0.f : sc[t] * inv;
        #pragma unroll
        for (int j = 0; j < 32; ++j) o[j] += wgt * vv[j];
    }

    uint4* xp = (uint4*)(X2 + (size_t)dh * BN * 32 + (size_t)n * 32);
    #pragma unroll
    for (int m4 = 0; m4 < 4; ++m4) {
        uint4 v;
        v.x = f2b(o[8 * m4 + 0]) | ((uint)f2b(o[8 * m4 + 1]) << 16);
        v.y = f2b(o[8 * m4 + 2]) | ((uint)f2b(o[8 * m4 + 3]) << 16);
        v.z = f2b(o[8 * m4 + 4]) | ((uint)f2b(o[8 * m4 + 5]) << 16);
        v.w = f2b(o[8 * m4 + 6]) | ((uint)f2b(o[8 * m4 + 7]) << 16);
        xp[m4] = v;
    }
}

__global__ __launch_bounds__(256) void attn2_k(
    const ushort* __restrict__ qkv2, ushort* __restrict__ X2)
{
    const int bid = blockIdx.x;                        // 800 linear
    const int dh  = bid & 7;                           // XCD = dh
    const int t2  = bid >> 3;                          // 0..99
    const int b   = t2 / 25;
    const int tile = t2 % 25;
    const int y0 = (tile / 5) * 16, x0 = (tile % 5) * 16;
    const bool inter = (y0 >= 16 && y0 <= 48 && x0 >= 16 && x0 <= 48);
    if (dh < 4) {
        if (inter) attn_px<2, false>(qkv2, X2, b, dh, y0, x0);
        else       attn_px<2, true >(qkv2, X2, b, dh, y0, x0);
    } else {
        if (inter) attn_px<3, false>(qkv2, X2, b, dh, y0, x0);
        else       attn_px<3, true >(qkv2, X2, b, dh, y0, x0);
    }
}

// ---------------------------------------------------------------------------
// Proj GEMM + epilogue: out[n][co] = X·Wp^T + bias + Y residual.
// Retiled 64n x 128o: 800 blocks (~3/CU co-resident). LDS 24 KB. 4 waves in
// 2x2 grid, each 32n x 64o, acc[2][4]. A staged from chunk-major X2: the XOR
// swizzle's bit-5 flip selects between the two 32-wide chunks spanned by
// BK=64 (chunk_sel). XCD-chunked dispatch like qkv (o fastest: A-tile
// L2-reuse across 2 o-blocks; W 128 KB L2-resident).
// ---------------------------------------------------------------------------
__global__ __launch_bounds__(256) void proj_mfma(
    const ushort* __restrict__ X2, const ushort* __restrict__ Wpb,
    const float* __restrict__ bp, const ushort* __restrict__ Yb,
    float* __restrict__ out)
{
    __shared__ __align__(16) ushort As[64 * 64];       //  8 KB
    __shared__ __align__(16) ushort Bs[128 * 64];      // 16 KB
    const int tid = threadIdx.x;
    const int lane = tid & 63;
    const int wave = tid >> 6;
    const int wr = wave >> 1, wc = wave & 1;
    const int l15 = lane & 15, quad = lane >> 4;

    const int bid = blockIdx.x;                  // grid = 800 linear
    const int swz = (bid & 7) * 100 + (bid >> 3);
    const int n0 = (swz >> 1) * 64;
    const int o0 = (swz & 1) * 128;

    const int srow8 = tid >> 3;
    const int scol  = ((tid & 7) * 8) ^ ((srow8 & 1) << 5);
    const int chunk_sel = ((tid >> 2) & 1) ^ (srow8 & 1);
    const int coff  = (tid & 3) * 8;
    const int par   = l15 & 1;

    floatx4 acc[2][4] = {};

    for (int k0 = 0; k0 < CDIM; k0 += 64) {
        const int cbase = k0 >> 5;
        const ushort* Achunk = X2 + (size_t)(cbase + chunk_sel) * BN * 32;
        #pragma unroll
        for (int r = 0; r < 2; ++r) {
            const int row = r * 32 + srow8;
            gload_lds16(&Achunk[(size_t)(n0 + row) * 32 + coff],
                        As + r * 2048 + wave * 512);
        }
        #pragma unroll
        for (int r = 0; r < 4; ++r) {
            const int row = r * 32 + srow8;
            gload_lds16(&Wpb[(size_t)(o0 + row) * CDIM + k0 + scol],
                        Bs + r * 2048 + wave * 512);
        }
        __syncthreads();
        #pragma unroll
        for (int s = 0; s < 2; ++s) {
            const int fc = ((s ^ par) << 5) + quad * 8;
            short8 af[2], bfr[4];
            #pragma unroll
            for (int i = 0; i < 2; ++i)
                af[i] = *(const short8*)(&As[(wr * 32 + i * 16 + l15) * 64 + fc]);
            #pragma unroll
            for (int j = 0; j < 4; ++j)
                bfr[j] = *(const short8*)(&Bs[(wc * 64 + j * 16 + l15) * 64 + fc]);
            #pragma unroll
            for (int i = 0; i < 2; ++i)
                #pragma unroll
                for (int j = 0; j < 4; ++j)
                    acc[i][j] = __builtin_amdgcn_mfma_f32_16x16x32_bf16(
                        bfr[j], af[i], acc[i][j], 0, 0, 0);   // swapped: rows=o
        }
        __syncthreads();
    }

    #pragma unroll
    for (int i = 0; i < 2; ++i) {
        const int n = n0 + wr * 32 + i * 16 + l15;
        #pragma unroll
        for (int j = 0; j < 4; ++j) {
            const int o4 = o0 + wc * 64 + j * 16 + quad * 4;   // 4 consecutive co
            const float4 bias = *(const float4*)(bp + o4);
            const ushort4 res = *(const ushort4*)(Yb + (size_t)n * CDIM + o4);
            float4 v;
            v.x = acc[i][j][0] + bias.x + b2f(res.x);
            v.y = acc[i][j][1] + bias.y + b2f(res.y);
            v.z = acc[i][j][2] + bias.z + b2f(res.z);
            v.w = acc[i][j][3] + bias.w + b2f(res.w);
            *(float4*)(out + (size_t)n * CDIM + o4) = v;
        }
    }
}

extern "C" void kernel_launch(void* const* d_in, const int* in_sizes, int n_in,
                              void* d_out, int out_size, void* d_ws, size_t ws_size,
                              hipStream_t stream) {
    const float* rgb    = (const float*)d_in[0];
    const float* ir     = (const float*)d_in[1];
    const float* w_qkv  = (const float*)d_in[2];
    const float* w_proj = (const float*)d_in[3];
    const float* b_proj = (const float*)d_in[4];
    float* out = (float*)d_out;

    ushort* qkv2 = (ushort*)d_ws;                    // 24 chunks * 25600*32 = 39.3 MB
    ushort* Yb   = qkv2 + (size_t)24 * BN * 32;      // 25600*256 = 13.1 MB
    ushort* X2   = Yb + (size_t)BN * CDIM;           // 8 chunks * 25600*32 = 13.1 MB
    ushort* Wqb  = X2 + (size_t)8 * BN * 32;         // 768*256
    ushort* Wpb  = Wqb + (size_t)QKVC * CDIM;        // 256*256

    cast_all_k<<<dim3(132, 8, NB), 256, 0, stream>>>(rgb, ir, w_qkv, w_proj,
                                                     Yb, Wqb, Wpb);
    gemm_qkv_mfma<<<dim3(1200), 256, 0, stream>>>(Yb, Wqb, qkv2);
    attn2_k<<<dim3(800), 256, 0, stream>>>(qkv2, X2);
    proj_mfma<<<dim3(800), 256, 0, stream>>>(X2, Wpb, b_proj, Yb, out);
}

// Round 5
// 137.938 us; speedup vs baseline: 1.0773x; 1.0162x over previous
//
#include <hip/hip_runtime.h>

#define HH 80
#define WW 80
#define NPIX 6400          // 80*80
#define NB 4
#define BN 25600           // NB * NPIX
#define CDIM 256
#define QKVC 768
#define SCALE 0.17677669529663689f   // 32^-0.5

typedef __attribute__((ext_vector_type(8))) short short8;
typedef __attribute__((ext_vector_type(4))) float floatx4;

__device__ __forceinline__ float b2f(ushort u) {
    return __uint_as_float(((uint)u) << 16);
}
__device__ __forceinline__ ushort f2b(float f) {
    uint u = __float_as_uint(f);
    return (ushort)((u + 0x7fffu + ((u >> 16) & 1u)) >> 16);   // RNE
}
__device__ __forceinline__ void unpack8(uint4 v, float* f) {
    f[0] = __uint_as_float(v.x << 16); f[1] = __uint_as_float(v.x & 0xffff0000u);
    f[2] = __uint_as_float(v.y << 16); f[3] = __uint_as_float(v.y & 0xffff0000u);
    f[4] = __uint_as_float(v.z << 16); f[5] = __uint_as_float(v.z & 0xffff0000u);
    f[6] = __uint_as_float(v.w << 16); f[7] = __uint_as_float(v.w & 0xffff0000u);
}
__device__ __forceinline__ void gload_lds16(const void* gptr, void* lptr) {
    __builtin_amdgcn_global_load_lds(
        (const __attribute__((address_space(1))) unsigned int*)gptr,
        (__attribute__((address_space(3))) unsigned int*)lptr,
        16, 0, 0);
}

// ---------------------------------------------------------------------------
// Fused cast kernel.
//  blocks x <  100: Yb[n][c] = bf16(concat(rgb, ir)) via LDS transpose tile
//  blocks x >= 100: cast w_qkv / w_proj to bf16 (flat)
// ---------------------------------------------------------------------------
__global__ __launch_bounds__(256) void cast_all_k(
    const float* __restrict__ rgb, const float* __restrict__ ir,
    const float* __restrict__ wq, const float* __restrict__ wp,
    ushort* __restrict__ Yb, ushort* __restrict__ wqb, ushort* __restrict__ wpb)
{
    const int tid = threadIdx.x;
    if (blockIdx.x >= 100) {
        int i = (((blockIdx.x - 100) * 8 + blockIdx.y) * 4 + blockIdx.z) * 256 + tid;
        if (i < QKVC * CDIM) wqb[i] = f2b(wq[i]);
        else                 wpb[i - QKVC * CDIM] = f2b(wp[i - QKVC * CDIM]);
        return;
    }
    __shared__ ushort T[32][72];
    const int pix0 = blockIdx.x * 64;
    const int cb = blockIdx.y;
    const int b = blockIdx.z;

    const int pl = tid & 63, cg = tid >> 6;
    #pragma unroll
    for (int cc = 0; cc < 32; cc += 4) {
        int c = cb * 32 + cc + cg;
        const float* src = (c < 128) ? (rgb + ((size_t)b * 128 + c) * NPIX)
                                     : (ir + ((size_t)b * 128 + (c - 128)) * NPIX);
        T[cc + cg][pl] = f2b(src[pix0 + pl]);
    }
    __syncthreads();
    const int nl = tid >> 2, c0 = (tid & 3) * 8;
    ushort tmp[8];
    #pragma unroll
    for (int j = 0; j < 8; ++j) tmp[j] = T[c0 + j][nl];
    uint4 v;
    v.x = tmp[0] | ((uint)tmp[1] << 16);
    v.y = tmp[2] | ((uint)tmp[3] << 16);
    v.z = tmp[4] | ((uint)tmp[5] << 16);
    v.w = tmp[6] | ((uint)tmp[7] << 16);
    *(uint4*)(&Yb[((size_t)(b * NPIX + pix0 + nl)) * CDIM + cb * 32 + c0]) = v;
}

// ---------------------------------------------------------------------------
// BK=64 MFMA NT GEMM body. 128x128 tile, 4 K-iters. Unpadded LDS [m][64] with
// parity-XOR swizzle: odd rows store their two 32-elem k-halves swapped
// (scol = k ^ ((row&1)<<5)), applied on the GLOBAL address so the
// global_load_lds DMA stays flat+contiguous (m104). Frag reads spread across
// all 32 banks -> conflict-free.
// MFMA operands swapped (o = A operand): acc reg r = o offset, lane&15 = n.
// ---------------------------------------------------------------------------
__device__ __forceinline__ void gemm_nt_body64(
    const ushort* __restrict__ A, const ushort* __restrict__ W,
    ushort* As, ushort* Bs, int n0, int o0, floatx4 acc[4][4])
{
    const int tid = threadIdx.x;
    const int lane = tid & 63;
    const int wave = tid >> 6;
    const int wr = wave >> 1, wc = wave & 1;
    const int l15 = lane & 15, quad = lane >> 4;

    const int srow8 = tid >> 3;                        // row within 32-row round
    const int scol  = ((tid & 7) * 8) ^ ((srow8 & 1) << 5);
    const int par   = l15 & 1;                         // frag-row parity

    for (int k0 = 0; k0 < CDIM; k0 += 64) {
        #pragma unroll
        for (int r = 0; r < 4; ++r) {
            const int row = r * 32 + srow8;
            gload_lds16(&A[(size_t)(n0 + row) * CDIM + k0 + scol],
                        As + r * 2048 + wave * 512);
            gload_lds16(&W[(size_t)(o0 + row) * CDIM + k0 + scol],
                        Bs + r * 2048 + wave * 512);
        }
        __syncthreads();
        #pragma unroll
        for (int s = 0; s < 2; ++s) {
            const int fc = ((s ^ par) << 5) + quad * 8;
            short8 af[4], bfr[4];
            #pragma unroll
            for (int i = 0; i < 4; ++i)
                af[i] = *(const short8*)(&As[(wr * 64 + i * 16 + l15) * 64 + fc]);
            #pragma unroll
            for (int j = 0; j < 4; ++j)
                bfr[j] = *(const short8*)(&Bs[(wc * 64 + j * 16 + l15) * 64 + fc]);
            #pragma unroll
            for (int i = 0; i < 4; ++i)
                #pragma unroll
                for (int j = 0; j < 4; ++j)
                    acc[i][j] = __builtin_amdgcn_mfma_f32_16x16x32_bf16(
                        bfr[j], af[i], acc[i][j], 0, 0, 0);   // swapped: rows=o
        }
        __syncthreads();
    }
}

// ---------------------------------------------------------------------------
// QKV GEMM. Output chunk-major qkv2[chunk][n][32], chunk = o>>5
// (chunk 0..7 = Q(dil,head), 8..15 = K, 16..23 = V). 8B packed stores.
// XCD-chunked dispatch: 1200 blocks, bid%8 selects XCD; within an XCD's 150
// consecutive slots, o iterates fastest so the 6 o-blocks sharing one A-tile
// run back-to-back on the same XCD -> A reads L2-hit; W L2-resident.
// ---------------------------------------------------------------------------
__global__ __launch_bounds__(256) void gemm_qkv_mfma(
    const ushort* __restrict__ Yb, const ushort* __restrict__ Wb,
    ushort* __restrict__ qkv2)
{
    __shared__ __align__(16) ushort As[128 * 64];
    __shared__ __align__(16) ushort Bs[128 * 64];
    const int tid = threadIdx.x;
    const int lane = tid & 63;
    const int wave = tid >> 6;
    const int wr = wave >> 1, wc = wave & 1;
    const int l15 = lane & 15, quad = lane >> 4;

    const int bid = blockIdx.x;                  // grid = 1200 linear
    const int swz = (bid & 7) * 150 + (bid >> 3);
    const int n0 = (swz / 6) * 128;
    const int o0 = (swz % 6) * 128;

    floatx4 acc[4][4] = {};
    gemm_nt_body64(Yb, Wb, As, Bs, n0, o0, acc);

    #pragma unroll
    for (int i = 0; i < 4; ++i) {
        const int n = n0 + wr * 64 + i * 16 + l15;
        #pragma unroll
        for (int j = 0; j < 4; ++j) {
            const int o4 = o0 + wc * 64 + j * 16 + quad * 4;   // 4 consecutive o
            uint2 v;
            v.x = f2b(acc[i][j][0]) | ((uint)f2b(acc[i][j][1]) << 16);
            v.y = f2b(acc[i][j][2]) | ((uint)f2b(acc[i][j][3]) << 16);
            *(uint2*)(qkv2 + (size_t)(o4 >> 5) * BN * 32 + (size_t)n * 32 + (o4 & 31)) = v;
        }
    }
}

// ---------------------------------------------------------------------------
// Attention phase of the fused kernel (per thread: one pixel x one (dil,head)
// chunk, direct-L2 K/V loads as in R4). Output goes to the LDS X-tile
// Xl[32 px][256 ch] with slot-XOR swizzle: 16B slot index
// (dh*4+m4) ^ (px&7), giving bank-floor ds_write_b128 / ds_read_b128.
// OOB semantics: score 0 participates in softmax denom; V contribution 0.
// ---------------------------------------------------------------------------
template<int D, bool EDGE>
__device__ __forceinline__ void attn_phase(
    const ushort* __restrict__ qkv2, ushort* Xl,
    int b, int dh, int y0, int x0, int px)
{
    const int py = px >> 3, pxx = px & 7;
    const int yy0 = y0 + py, xx0 = x0 + pxx;
    const int n = b * NPIX + yy0 * WW + xx0;
    const ushort* Qc = qkv2 + (size_t)dh * BN * 32;
    const ushort* Kc = qkv2 + (size_t)(8 + dh) * BN * 32;
    const ushort* Vc = qkv2 + (size_t)(16 + dh) * BN * 32;

    float q[32];
    {
        const uint4* qp = (const uint4*)(Qc + (size_t)n * 32);
        uint4 v0 = qp[0], v1 = qp[1], v2 = qp[2], v3 = qp[3];
        unpack8(v0, q); unpack8(v1, q + 8); unpack8(v2, q + 16); unpack8(v3, q + 24);
    }

    float sc[9];
    #pragma unroll
    for (int t = 0; t < 9; ++t) {
        const int dy = t / 3 - 1, dx = t % 3 - 1;
        int yy = yy0 + dy * D, xx = xx0 + dx * D;
        bool ok = true;
        if (EDGE) {
            ok = (yy >= 0 && yy < HH && xx >= 0 && xx < WW);
            yy = min(max(yy, 0), HH - 1);
            xx = min(max(xx, 0), WW - 1);
        }
        const uint4* kp = (const uint4*)(Kc + (size_t)(b * NPIX + yy * WW + xx) * 32);
        uint4 k0 = kp[0], k1 = kp[1], k2 = kp[2], k3 = kp[3];
        float kv[32];
        unpack8(k0, kv); unpack8(k1, kv + 8); unpack8(k2, kv + 16); unpack8(k3, kv + 24);
        float s = 0.f;
        #pragma unroll
        for (int j = 0; j < 32; ++j) s += q[j] * kv[j];
        sc[t] = (EDGE && !ok) ? 0.f : s * SCALE;   // OOB: exact 0 (in denom)
    }

    float m = sc[0];
    #pragma unroll
    for (int t = 1; t < 9; ++t) m = fmaxf(m, sc[t]);
    float sum = 0.f;
    #pragma unroll
    for (int t = 0; t < 9; ++t) { sc[t] = __expf(sc[t] - m); sum += sc[t]; }
    const float inv = 1.f / sum;

    float o[32];
    #pragma unroll
    for (int j = 0; j < 32; ++j) o[j] = 0.f;
    #pragma unroll
    for (int t = 0; t < 9; ++t) {
        const int dy = t / 3 - 1, dx = t % 3 - 1;
        int yy = yy0 + dy * D, xx = xx0 + dx * D;
        bool ok = true;
        if (EDGE) {
            ok = (yy >= 0 && yy < HH && xx >= 0 && xx < WW);
            yy = min(max(yy, 0), HH - 1);
            xx = min(max(xx, 0), WW - 1);
        }
        const uint4* vp = (const uint4*)(Vc + (size_t)(b * NPIX + yy * WW + xx) * 32);
        uint4 v0 = vp[0], v1 = vp[1], v2 = vp[2], v3 = vp[3];
        float vv[32];
        unpack8(v0, vv); unpack8(v1, vv + 8); unpack8(v2, vv + 16); unpack8(v3, vv + 24);
        const float wgt = (EDGE && !ok) ? 0.f : sc[t] * inv;
        #pragma unroll
        for (int j = 0; j < 32; ++j) o[j] += wgt * vv[j];
    }

    #pragma unroll
    for (int m4 = 0; m4 < 4; ++m4) {
        uint4 v;
        v.x = f2b(o[8 * m4 + 0]) | ((uint)f2b(o[8 * m4 + 1]) << 16);
        v.y = f2b(o[8 * m4 + 2]) | ((uint)f2b(o[8 * m4 + 3]) << 16);
        v.z = f2b(o[8 * m4 + 4]) | ((uint)f2b(o[8 * m4 + 5]) << 16);
        v.w = f2b(o[8 * m4 + 6]) | ((uint)f2b(o[8 * m4 + 7]) << 16);
        const int slot = (dh * 4 + m4) ^ (px & 7);
        *(uint4*)(&Xl[px * 256 + slot * 8]) = v;
    }
}

// ---------------------------------------------------------------------------
// FUSED attention + projection. One block = (b, 4x8 pixel tile).
// Phase A: 256 threads = 32 px x 8 (dil,head); each thread does R4's
//   per-pixel direct-L2 attention and writes 32 ch to the LDS X-tile.
//   (waves 0-1: dh 0-3 = D2; waves 2-3: dh 4-7 = D3 -- no intra-wave div.)
// Phase B: proj GEMM tile 32n x 256o x 256k. Wp staged per 64-k slice into
//   Bs via DMA+scol (proven path); X frags read from the swizzled LDS tile.
//   Epilogue: bias + Yb residual + f32 store. Kills the X2 round-trip
//   (26 MB) and one kernel launch/ramp/tail.
// Grid 800 linear, XCD-chunked (bid&7 = XCD): each XCD owns 100 consecutive
// (b, tile) slots -> region-local K/V working set ~3.3 MB, L2-resident.
// LDS 48 KB -> 3 blocks/CU.
// ---------------------------------------------------------------------------
__global__ __launch_bounds__(256) void attn_proj_k(
    const ushort* __restrict__ qkv2, const ushort* __restrict__ Wpb,
    const float* __restrict__ bp, const ushort* __restrict__ Yb,
    float* __restrict__ out)
{
    __shared__ __align__(16) ushort Xl[32 * 256];   // 16 KB
    __shared__ __align__(16) ushort Bs[256 * 64];   // 32 KB
    const int tid = threadIdx.x;
    const int bid = blockIdx.x;                     // 800
    const int swz = (bid & 7) * 100 + (bid >> 3);
    const int b  = swz / 200;
    const int t  = swz % 200;
    const int y0 = (t / 10) * 4, x0 = (t % 10) * 8;
    const bool inter = (y0 >= 4 && y0 <= 72 && x0 >= 8 && x0 <= 64);

    const int px = tid & 31;
    const int dh = tid >> 5;

    if (dh < 4) {
        if (inter) attn_phase<2, false>(qkv2, Xl, b, dh, y0, x0, px);
        else       attn_phase<2, true >(qkv2, Xl, b, dh, y0, x0, px);
    } else {
        if (inter) attn_phase<3, false>(qkv2, Xl, b, dh, y0, x0, px);
        else       attn_phase<3, true >(qkv2, Xl, b, dh, y0, x0, px);
    }
    __syncthreads();                                 // X-tile complete

    const int lane = tid & 63;
    const int wave = tid >> 6;
    const int l15 = lane & 15, quad = lane >> 4;
    const int srow8 = tid >> 3;
    const int scol  = ((tid & 7) * 8) ^ ((srow8 & 1) << 5);
    const int par   = l15 & 1;

    floatx4 acc[2][4] = {};
    for (int k0 = 0; k0 < CDIM; k0 += 64) {
        #pragma unroll
        for (int r = 0; r < 8; ++r) {                // stage Wp[256 o][64 k]
            const int row = r * 32 + srow8;
            gload_lds16(&Wpb[(size_t)row * CDIM + k0 + scol],
                        Bs + r * 2048 + wave * 512);
        }
        __syncthreads();                             // DMA drained
        #pragma unroll
        for (int s = 0; s < 2; ++s) {
            const int fc = ((s ^ par) << 5) + quad * 8;
            short8 af[2], bfr[4];
            #pragma unroll
            for (int i = 0; i < 2; ++i) {
                const int row = i * 16 + l15;        // px row
                const int slot = ((k0 >> 3) + s * 4 + quad) ^ (row & 7);
                af[i] = *(const short8*)(&Xl[row * 256 + slot * 8]);
            }
            #pragma unroll
            for (int j = 0; j < 4; ++j)
                bfr[j] = *(const short8*)(&Bs[(wave * 64 + j * 16 + l15) * 64 + fc]);
            #pragma unroll
            for (int i = 0; i < 2; ++i)
                #pragma unroll
                for (int j = 0; j < 4; ++j)
                    acc[i][j] = __builtin_amdgcn_mfma_f32_16x16x32_bf16(
                        bfr[j], af[i], acc[i][j], 0, 0, 0);   // swapped: rows=o
        }
        __syncthreads();                             // before Bs overwrite
    }

    #pragma unroll
    for (int i = 0; i < 2; ++i) {
        const int r15 = i * 16 + l15;
        const int n = b * NPIX + (y0 + (r15 >> 3)) * WW + (x0 + (r15 & 7));
        #pragma unroll
        for (int j = 0; j < 4; ++j) {
            const int o4 = wave * 64 + j * 16 + quad * 4;   // 4 consecutive co
            const float4 bias = *(const float4*)(bp + o4);
            const ushort4 res = *(const ushort4*)(Yb + (size_t)n * CDIM + o4);
            float4 v;
            v.x = acc[i][j][0] + bias.x + b2f(res.x);
            v.y = acc[i][j][1] + bias.y + b2f(res.y);
            v.z = acc[i][j][2] + bias.z + b2f(res.z);
            v.w = acc[i][j][3] + bias.w + b2f(res.w);
            *(float4*)(out + (size_t)n * CDIM + o4) = v;
        }
    }
}

extern "C" void kernel_launch(void* const* d_in, const int* in_sizes, int n_in,
                              void* d_out, int out_size, void* d_ws, size_t ws_size,
                              hipStream_t stream) {
    const float* rgb    = (const float*)d_in[0];
    const float* ir     = (const float*)d_in[1];
    const float* w_qkv  = (const float*)d_in[2];
    const float* w_proj = (const float*)d_in[3];
    const float* b_proj = (const float*)d_in[4];
    float* out = (float*)d_out;

    ushort* qkv2 = (ushort*)d_ws;                    // 24 chunks * 25600*32 = 39.3 MB
    ushort* Yb   = qkv2 + (size_t)24 * BN * 32;      // 25600*256 = 13.1 MB
    ushort* Wqb  = Yb + (size_t)BN * CDIM;           // 768*256
    ushort* Wpb  = Wqb + (size_t)QKVC * CDIM;        // 256*256

    cast_all_k<<<dim3(132, 8, NB), 256, 0, stream>>>(rgb, ir, w_qkv, w_proj,
                                                     Yb, Wqb, Wpb);
    gemm_qkv_mfma<<<dim3(1200), 256, 0, stream>>>(Yb, Wqb, qkv2);
    attn_proj_k<<<dim3(800), 256, 0, stream>>>(qkv2, Wpb, b_proj, Yb, out);
}